// Round 1
// baseline (692.827 us; speedup 1.0000x reference)
//
#include <hip/hip_runtime.h>
#include <math.h>

#define B_ 8
#define Q_ 150
#define C_ 134
#define T_ 32
#define H_ 160
#define W_ 160
#define P_ 12544
#define G_ 2                 // q's per block in main kernel
#define CHUNK 256
#define NCHUNK (P_ / CHUNK)  // 49

struct Samp {
  int i00, i01, i10, i11;
  float w00, w01, w10, w11;
};

__device__ __forceinline__ Samp make_samp(float cx, float cy) {
  float x = cx * (float)W_ - 0.5f;
  float y = cy * (float)H_ - 0.5f;
  float x0f = floorf(x), y0f = floorf(y);
  float tx = x - x0f, ty = y - y0f;
  int x0 = (int)x0f, y0 = (int)y0f;
  int x1 = x0 + 1, y1 = y0 + 1;
  bool vx0 = (x0 >= 0) && (x0 < W_);
  bool vx1 = (x1 >= 0) && (x1 < W_);
  bool vy0 = (y0 >= 0) && (y0 < H_);
  bool vy1 = (y1 >= 0) && (y1 < H_);
  int cx0 = min(max(x0, 0), W_ - 1), cx1 = min(max(x1, 0), W_ - 1);
  int cy0 = min(max(y0, 0), H_ - 1), cy1 = min(max(y1, 0), H_ - 1);
  Samp s;
  s.i00 = cy0 * W_ + cx0;
  s.i01 = cy0 * W_ + cx1;
  s.i10 = cy1 * W_ + cx0;
  s.i11 = cy1 * W_ + cx1;
  float w00 = (1.f - tx) * (1.f - ty);
  float w01 = tx * (1.f - ty);
  float w10 = (1.f - tx) * ty;
  float w11 = tx * ty;
  s.w00 = (vx0 && vy0) ? w00 : 0.f;
  s.w01 = (vx1 && vy0) ? w01 : 0.f;
  s.w10 = (vx0 && vy1) ? w10 : 0.f;
  s.w11 = (vx1 && vy1) ? w11 : 0.f;
  return s;
}

__device__ __forceinline__ float waveReduceSum(float v) {
#pragma unroll
  for (int m = 32; m >= 1; m >>= 1) v += __shfl_xor(v, m, 64);
  return v;
}

__device__ __forceinline__ float waveReduceMax(float v) {
#pragma unroll
  for (int m = 32; m >= 1; m >>= 1) v = fmaxf(v, __shfl_xor(v, m, 64));
  return v;
}

__device__ __forceinline__ float blockReduceSum(float v, float* red) {
  v = waveReduceSum(v);
  int wave = threadIdx.x >> 6;
  __syncthreads();
  if ((threadIdx.x & 63) == 0) red[wave] = v;
  __syncthreads();
  return red[0] + red[1] + red[2] + red[3];
}

__device__ __forceinline__ float blockReduceMax(float v, float* red) {
  v = waveReduceMax(v);
  int wave = threadIdx.x >> 6;
  __syncthreads();
  if ((threadIdx.x & 63) == 0) red[wave] = v;
  __syncthreads();
  return fmaxf(fmaxf(red[0], red[1]), fmaxf(red[2], red[3]));
}

// ---------------- kernel 1: sample target masks -> tm[B][T][P] ----------------
__launch_bounds__(256) __global__
void tm_kernel(const float* __restrict__ mask_labels,
               const float* __restrict__ coords,
               float* __restrict__ tm) {
  int pc = blockIdx.x;  // 0..48
  int t = blockIdx.y;   // 0..31
  int b = blockIdx.z;   // 0..7
  int p = pc * CHUNK + threadIdx.x;
  const float2* c2 = (const float2*)coords;
  float2 cc = c2[(size_t)b * P_ + p];
  Samp s = make_samp(cc.x, cc.y);
  const float* img = mask_labels + (size_t)(b * T_ + t) * (H_ * W_);
  float v = s.w00 * img[s.i00] + s.w01 * img[s.i01] + s.w10 * img[s.i10] +
            s.w11 * img[s.i11];
  tm[(size_t)(b * T_ + t) * P_ + p] = v;
}

// ---------------- kernel 1b: S_tm[b][t] = sum_p tm ----------------
__launch_bounds__(256) __global__
void stm_kernel(const float* __restrict__ tm, float* __restrict__ S_tm) {
  __shared__ float red[64];
  int bt = blockIdx.x;  // 0..B*T-1
  const float* row = tm + (size_t)bt * P_;
  float s = 0.f;
  for (int p = threadIdx.x; p < P_; p += 256) s += row[p];
  float tot = blockReduceSum(s, red);
  if (threadIdx.x == 0) S_tm[bt] = tot;
}

// ---------------- kernel 2: main cost ----------------
__launch_bounds__(256) __global__
void main_kernel(const float* __restrict__ masks_q,  // [B,Q,H,W]
                 const float* __restrict__ class_q,  // [B,Q,C]
                 const int* __restrict__ labels,     // [B,T]
                 const float* __restrict__ coords,   // [B,P,2]
                 const float* __restrict__ tm,       // [B,T,P]
                 const float* __restrict__ S_tm,     // [B,T]
                 float* __restrict__ out)            // [B,Q,T]
{
  const int tid = threadIdx.x;
  const int b = blockIdx.y;
  const int q0 = blockIdx.x * G_;

  __shared__ float pmL[G_][CHUNK];
  __shared__ float sigL[G_][CHUNK];
  __shared__ float red[64];
  __shared__ float cls_max[G_], cls_den[G_];
  __shared__ float S_sp_s[G_], S_sig_s[G_];
  __shared__ float Dlin_s[G_][T_], Dsig_s[G_][T_];

  // phase 0: class softmax stats for each q in this block
#pragma unroll
  for (int g = 0; g < G_; ++g) {
    const float* cl = class_q + (size_t)(b * Q_ + q0 + g) * C_;
    float v = (tid < C_) ? cl[tid] : -INFINITY;
    float m = blockReduceMax(v, red);
    float e = (tid < C_) ? __expf(v - m) : 0.f;
    float d = blockReduceSum(e, red);
    if (tid == 0) {
      cls_max[g] = m;
      cls_den[g] = d;
    }
  }

  float S_sp[G_], S_sig[G_], accL[G_], accS[G_];
#pragma unroll
  for (int g = 0; g < G_; ++g) {
    S_sp[g] = 0.f;
    S_sig[g] = 0.f;
    accL[g] = 0.f;
    accS[g] = 0.f;
  }

  const int t_lane = tid >> 3;  // 0..31
  const int pg = tid & 7;       // 0..7

  const float* mbase = masks_q + (size_t)(b * Q_ + q0) * (H_ * W_);
  const float* tmrow = tm + (size_t)(b * T_ + t_lane) * P_;
  const float2* c2 = (const float2*)coords;

  for (int c = 0; c < NCHUNK; ++c) {
    int p = c * CHUNK + tid;
    float2 cc = c2[(size_t)b * P_ + p];
    Samp s = make_samp(cc.x, cc.y);
#pragma unroll
    for (int g = 0; g < G_; ++g) {
      const float* img = mbase + (size_t)g * (H_ * W_);
      float pm = s.w00 * img[s.i00] + s.w01 * img[s.i01] +
                 s.w10 * img[s.i10] + s.w11 * img[s.i11];
      float sp = fmaxf(pm, 0.f) + __logf(1.f + __expf(-fabsf(pm)));
      float sg = 1.f / (1.f + __expf(-pm));
      S_sp[g] += sp;
      S_sig[g] += sg;
      pmL[g][tid] = pm;
      sigL[g][tid] = sg;
    }
    __syncthreads();
#pragma unroll
    for (int j = 0; j < 8; ++j) {
      int pl = (j * 8 + pg) * 4;
      float4 tv = *(const float4*)&tmrow[c * CHUNK + pl];
#pragma unroll
      for (int g = 0; g < G_; ++g) {
        float4 pv = *(const float4*)&pmL[g][pl];
        float4 sv = *(const float4*)&sigL[g][pl];
        accL[g] += pv.x * tv.x + pv.y * tv.y + pv.z * tv.z + pv.w * tv.w;
        accS[g] += sv.x * tv.x + sv.y * tv.y + sv.z * tv.z + sv.w * tv.w;
      }
    }
    __syncthreads();
  }

  // reduce accL/accS across the 8 p-groups (lanes differing in bits 0..2)
#pragma unroll
  for (int g = 0; g < G_; ++g) {
    float aL = accL[g], aS = accS[g];
#pragma unroll
    for (int m = 1; m <= 4; m <<= 1) {
      aL += __shfl_xor(aL, m, 64);
      aS += __shfl_xor(aS, m, 64);
    }
    if (pg == 0) {
      Dlin_s[g][t_lane] = aL;
      Dsig_s[g][t_lane] = aS;
    }
  }

  // block-wide sums of S_sp / S_sig
#pragma unroll
  for (int g = 0; g < G_; ++g) {
    float v = blockReduceSum(S_sp[g], red);
    if (tid == 0) S_sp_s[g] = v;
    v = blockReduceSum(S_sig[g], red);
    if (tid == 0) S_sig_s[g] = v;
  }
  __syncthreads();

  if (tid < T_) {
    int t = tid;
    int lbl = labels[b * T_ + t];
    float stm = S_tm[b * T_ + t];
#pragma unroll
    for (int g = 0; g < G_; ++g) {
      int q = q0 + g;
      float Dlin = Dlin_s[g][t];
      float Dsig = Dsig_s[g][t];
      float cmask = (S_sp_s[g] - Dlin) * (1.f / (float)P_);
      float dice = 1.f - (2.f * Dsig + 1.f) / (S_sig_s[g] + stm + 1.f);
      float lg = class_q[(size_t)(b * Q_ + q) * C_ + lbl];
      float prob = __expf(lg - cls_max[g]) / cls_den[g];
      out[(size_t)(b * Q_ + q) * T_ + t] = 5.f * cmask + 5.f * dice - prob;
    }
  }
}

extern "C" void kernel_launch(void* const* d_in, const int* in_sizes, int n_in,
                              void* d_out, int out_size, void* d_ws,
                              size_t ws_size, hipStream_t stream) {
  const float* masks_q = (const float*)d_in[0];       // [B,Q,H,W]
  const float* class_q = (const float*)d_in[1];       // [B,Q,C]
  const float* mask_labels = (const float*)d_in[2];   // [B,T,H,W]
  const int* class_labels = (const int*)d_in[3];      // [B,T]
  const float* coords = (const float*)d_in[4];        // [B,P,2]
  float* out = (float*)d_out;

  float* tm = (float*)d_ws;                       // B*T*P floats
  float* S_tm = tm + (size_t)B_ * T_ * P_;        // B*T floats

  tm_kernel<<<dim3(NCHUNK, T_, B_), 256, 0, stream>>>(mask_labels, coords, tm);
  stm_kernel<<<B_ * T_, 256, 0, stream>>>(tm, S_tm);
  main_kernel<<<dim3(Q_ / G_, B_), 256, 0, stream>>>(masks_q, class_q,
                                                     class_labels, coords, tm,
                                                     S_tm, out);
}